// Round 2
// baseline (266.928 us; speedup 1.0000x reference)
//
#include <hip/hip_runtime.h>
#include <stdint.h>

#define HW 262144            // 512*512
#define ACQ_N 2097152        // 8*1*512*512

// ---------- threefry2x32 (JAX-exact, 20 rounds) ----------
__host__ __device__ __forceinline__ void tf2x32(uint32_t k0, uint32_t k1,
                                                uint32_t c0, uint32_t c1,
                                                uint32_t& o0, uint32_t& o1) {
  const uint32_t ks2 = k0 ^ k1 ^ 0x1BD11BDAu;
  uint32_t x0 = c0 + k0, x1 = c1 + k1;
#define TFR(r) { x0 += x1; x1 = (x1 << (r)) | (x1 >> (32 - (r))); x1 ^= x0; }
  TFR(13) TFR(15) TFR(26) TFR(6)
  x0 += k1;  x1 += ks2 + 1u;
  TFR(17) TFR(29) TFR(16) TFR(24)
  x0 += ks2; x1 += k0 + 2u;
  TFR(13) TFR(15) TFR(26) TFR(6)
  x0 += k0;  x1 += k1 + 3u;
  TFR(17) TFR(29) TFR(16) TFR(24)
  x0 += k1;  x1 += ks2 + 4u;
  TFR(13) TFR(15) TFR(26) TFR(6)
  x0 += ks2; x1 += k0 + 5u;
#undef TFR
  o0 = x0; o1 = x1;
}

// partitionable threefry random_bits(32): element i -> xor of cipher(key, hi=0, lo=i)
__device__ __forceinline__ uint32_t rbits32(uint32_t k0, uint32_t k1, uint32_t idx) {
  uint32_t o0, o1;
  tf2x32(k0, k1, 0u, idx, o0, o1);
  return o0 ^ o1;
}

__device__ __forceinline__ float unit_from_bits(uint32_t b) {
  return __uint_as_float((b >> 9) | 0x3F800000u) - 1.0f;
}

// XLA ErfInv32 (Giles) — both branches predicated (no wave divergence)
__device__ __forceinline__ float erfinv_f(float x) {
  float w = -log1pf(-x * x);
  // near branch (w < 5)
  float wn = w - 2.5f;
  float pn = 2.81022636e-08f;
  pn = fmaf(pn, wn, 3.43273939e-07f);
  pn = fmaf(pn, wn, -3.5233877e-06f);
  pn = fmaf(pn, wn, -4.39150654e-06f);
  pn = fmaf(pn, wn, 0.00021858087f);
  pn = fmaf(pn, wn, -0.00125372503f);
  pn = fmaf(pn, wn, -0.00417768164f);
  pn = fmaf(pn, wn, 0.246640727f);
  pn = fmaf(pn, wn, 1.50140941f);
  // far branch (w >= 5)
  float wf = sqrtf(w) - 3.0f;
  float pf = -0.000200214257f;
  pf = fmaf(pf, wf, 0.000100950558f);
  pf = fmaf(pf, wf, 0.00134934322f);
  pf = fmaf(pf, wf, -0.00367342844f);
  pf = fmaf(pf, wf, 0.00573950773f);
  pf = fmaf(pf, wf, -0.0076224613f);
  pf = fmaf(pf, wf, 0.00943887047f);
  pf = fmaf(pf, wf, 1.00167406f);
  pf = fmaf(pf, wf, 2.83297682f);
  float p = (w < 5.0f) ? pn : pf;
  return p * x;
}

__device__ __forceinline__ float normal_from_bits(uint32_t b) {
  float f = unit_from_bits(b);
  float u = fmaf(f, 2.0f, -0.99999994f);   // (hi-lo) rounds to exactly 2.0f
  u = fmaxf(-0.99999994f, u);
  return 1.41421356f * erfinv_f(u);
}

__device__ __forceinline__ float sample_val(float base, float fw, float fa, float gw,
                                            uint32_t ub, uint32_t nb) {
  float u = unit_from_bits(ub);
  u = fminf(fmaxf(u, 1e-6f), 0.999999f);   // jnp.clip(u, 1e-6, 1-1e-6)
  float t = -logf(u);                       // t in [~1e-6, 13.8], > 0
  float pw = exp2f(-fa * log2f(t));         // t ** (-fa), finite (fa<~6)
  float z = normal_from_bits(nb);
  float s = base + fw * pw + gw * z;
  return fminf(fmaxf(s, 0.0f), 1.0f);
}

// ---------- bias = relu(mean(inp[:,1])) ----------
__global__ __launch_bounds__(256) void bias_partial(const float* __restrict__ inp,
                                                    float* __restrict__ partial) {
  int blk = blockIdx.x;                 // 512 blocks: 8 batches x 64 chunks
  int b = blk >> 6, chunk = blk & 63;
  const float* src = inp + ((size_t)b * 5 + 1) * HW + (size_t)chunk * 4096;
  int t = threadIdx.x;
  float s = 0.0f;
#pragma unroll
  for (int k = 0; k < 16; ++k) s += src[t + k * 256];
  for (int off = 32; off; off >>= 1) s += __shfl_down(s, off);
  __shared__ float ws4[4];
  if ((t & 63) == 0) ws4[t >> 6] = s;
  __syncthreads();
  if (t == 0) partial[blk] = ws4[0] + ws4[1] + ws4[2] + ws4[3];
}

__global__ __launch_bounds__(512) void bias_final(const float* __restrict__ partial,
                                                  float* __restrict__ bias) {
  int t = threadIdx.x;                  // 512 threads = 8 batches x 64 lanes
  int b = t >> 6, lane = t & 63;
  float s = partial[b * 64 + lane];
  for (int off = 32; off; off >>= 1) s += __shfl_down(s, off);
  if (lane == 0) bias[b] = fmaxf(s * (1.0f / 262144.0f), 0.0f);
}

// ---------- main: one thread per output pixel ----------
__global__ __launch_bounds__(256) void acquire_main(
    const float* __restrict__ inp, const int* __restrict__ frames,
    const float* __restrict__ bias, float* __restrict__ out,
    uint32_t ku0, uint32_t ku1, uint32_t kn0, uint32_t kn1) {
  int b = blockIdx.x >> 10;                         // 1024 blocks per batch
  int rem = ((blockIdx.x & 1023) << 8) | threadIdx.x;

  const float* pb = inp + (size_t)b * 5 * HW;
  float img = pb[rem];
  float fw  = fmaxf(pb[2 * HW + rem], 0.0f);
  float fa  = fmaxf(pb[3 * HW + rem], 0.0f);
  float gw  = fmaxf(pb[4 * HW + rem], 0.0f);
  float base = img + bias[b];

  int nf = frames[b];                               // block-uniform
  uint32_t i0 = (uint32_t)(b * 16) * (uint32_t)HW + (uint32_t)rem;

  float acc = 0.0f;
  for (int f = 0; f < nf; ++f) {
    uint32_t idx = i0 + (uint32_t)f * (uint32_t)HW; // linear idx in (8,16,512,512)
    uint32_t ub = rbits32(ku0, ku1, idx);
    uint32_t nb = rbits32(kn0, kn1, idx);
    acc += sample_val(base, fw, fa, gw, ub, nb);
  }
  out[(size_t)b * HW + rem] = acc / (float)nf;

  // center = clip(base + fw * (1/(fa+1))**fa, 0, 1)
  float pw = exp2f(fa * log2f(1.0f / (fa + 1.0f)));
  float c  = fminf(fmaxf(base + fw * pw, 0.0f), 1.0f);
  out[ACQ_N + (size_t)b * HW + rem] = c;
}

extern "C" void kernel_launch(void* const* d_in, const int* in_sizes, int n_in,
                              void* d_out, int out_size, void* d_ws, size_t ws_size,
                              hipStream_t stream) {
  const float* inp    = (const float*)d_in[0];
  const int*   frames = (const int*)d_in[1];
  float* out = (float*)d_out;
  float* ws  = (float*)d_ws;
  float* partial = ws;        // 512 floats
  float* bias    = ws + 512;  // 8 floats

  // jax_threefry_partitionable=True (JAX >= 0.5 default):
  // split(key(42)) foldlike: ku = cipher((0,42),(0,0)), kn = cipher((0,42),(0,1))
  uint32_t ku0, ku1, kn0, kn1;
  tf2x32(0u, 42u, 0u, 0u, ku0, ku1);
  tf2x32(0u, 42u, 0u, 1u, kn0, kn1);

  bias_partial<<<dim3(512), dim3(256), 0, stream>>>(inp, partial);
  bias_final<<<dim3(1), dim3(512), 0, stream>>>(partial, bias);
  acquire_main<<<dim3(8192), dim3(256), 0, stream>>>(inp, frames, bias, out,
                                                     ku0, ku1, kn0, kn1);
}

// Round 3
// 203.945 us; speedup vs baseline: 1.3088x; 1.3088x over previous
//
#include <hip/hip_runtime.h>
#include <stdint.h>

#define HW 262144            // 512*512
#define ACQ_N 2097152        // 8*1*512*512

// hw-native transcendentals (1 instr each; ~1 ulp)
#define LOG2F(x) __builtin_amdgcn_logf(x)    // v_log_f32 = log2
#define EXP2F(x) __builtin_amdgcn_exp2f(x)   // v_exp_f32 = 2^x
#define SQRTF(x) __builtin_amdgcn_sqrtf(x)   // v_sqrt_f32
#define RCPF(x)  __builtin_amdgcn_rcpf(x)    // v_rcp_f32

// ---------- threefry2x32 (JAX-exact, 20 rounds) ----------
__host__ __device__ __forceinline__ void tf2x32(uint32_t k0, uint32_t k1,
                                                uint32_t c0, uint32_t c1,
                                                uint32_t& o0, uint32_t& o1) {
  const uint32_t ks2 = k0 ^ k1 ^ 0x1BD11BDAu;
  uint32_t x0 = c0 + k0, x1 = c1 + k1;
#define TFR(r) { x0 += x1; x1 = (x1 << (r)) | (x1 >> (32 - (r))); x1 ^= x0; }
  TFR(13) TFR(15) TFR(26) TFR(6)
  x0 += k1;  x1 += ks2 + 1u;
  TFR(17) TFR(29) TFR(16) TFR(24)
  x0 += ks2; x1 += k0 + 2u;
  TFR(13) TFR(15) TFR(26) TFR(6)
  x0 += k0;  x1 += k1 + 3u;
  TFR(17) TFR(29) TFR(16) TFR(24)
  x0 += k1;  x1 += ks2 + 4u;
  TFR(13) TFR(15) TFR(26) TFR(6)
  x0 += ks2; x1 += k0 + 5u;
#undef TFR
  o0 = x0; o1 = x1;
}

// partitionable threefry random_bits(32): element i -> xor of cipher(key, 0, i)
__device__ __forceinline__ uint32_t rbits32(uint32_t k0, uint32_t k1, uint32_t idx) {
  uint32_t o0, o1;
  tf2x32(k0, k1, 0u, idx, o0, o1);
  return o0 ^ o1;
}

__device__ __forceinline__ float unit_from_bits(uint32_t b) {
  return __uint_as_float((b >> 9) | 0x3F800000u) - 1.0f;
}

// z = sqrt(2)*erfinv(x): Giles poly with all coeffs pre-scaled by sqrt(2).
// Both branches predicated (no wave divergence). log1p(-x^2) via
// ln2 * v_log(fma(-x,x,1)) — fma keeps the cancellation exact.
__device__ __forceinline__ float sqrt2_erfinv(float x) {
  float ome = fmaf(-x, x, 1.0f);                // 1 - x^2, single rounding
  float w = -0.69314718056f * LOG2F(ome);
  // near branch (w < 5)
  float wn = w - 2.5f;
  float pn = 3.974065e-08f;
  pn = fmaf(pn, wn, 4.854641e-07f);
  pn = fmaf(pn, wn, -4.982823e-06f);
  pn = fmaf(pn, wn, -6.210531e-06f);
  pn = fmaf(pn, wn, 3.091200e-04f);
  pn = fmaf(pn, wn, -1.773035e-03f);
  pn = fmaf(pn, wn, -5.908135e-03f);
  pn = fmaf(pn, wn, 3.488029e-01f);
  pn = fmaf(pn, wn, 2.123314e+00f);
  // far branch (w >= 5)
  float wf = SQRTF(w) - 3.0f;
  float pf = -2.831458e-04f;
  pf = fmaf(pf, wf, 1.427657e-04f);
  pf = fmaf(pf, wf, 1.908260e-03f);
  pf = fmaf(pf, wf, -5.195013e-03f);
  pf = fmaf(pf, wf, 8.116892e-03f);
  pf = fmaf(pf, wf, -1.0779791e-02f);
  pf = fmaf(pf, wf, 1.3348579e-02f);
  pf = fmaf(pf, wf, 1.416582e+00f);
  pf = fmaf(pf, wf, 4.006434e+00f);
  float p = (w < 5.0f) ? pn : pf;
  return p * x;
}

// ---------- bias partial sums: relu(mean(inp[:,1])) stage 1 ----------
__global__ __launch_bounds__(256) void bias_partial(const float* __restrict__ inp,
                                                    float* __restrict__ partial) {
  int blk = blockIdx.x;                 // 512 blocks: 8 batches x 64 chunks
  int b = blk >> 6, chunk = blk & 63;
  const float* src = inp + ((size_t)b * 5 + 1) * HW + (size_t)chunk * 4096;
  int t = threadIdx.x;
  float s = 0.0f;
#pragma unroll
  for (int k = 0; k < 16; ++k) s += src[t + k * 256];
  for (int off = 32; off; off >>= 1) s += __shfl_down(s, off);
  __shared__ float ws4[4];
  if ((t & 63) == 0) ws4[t >> 6] = s;
  __syncthreads();
  if (t == 0) partial[blk] = ws4[0] + ws4[1] + ws4[2] + ws4[3];
}

// ---------- main: one thread per output pixel; bias finalized in-block ----------
__global__ __launch_bounds__(256) void acquire_main(
    const float* __restrict__ inp, const int* __restrict__ frames,
    const float* __restrict__ partial, float* __restrict__ out,
    uint32_t ku0, uint32_t ku1, uint32_t kn0, uint32_t kn1) {
  int b = blockIdx.x >> 10;                         // 1024 blocks per batch
  int rem = ((blockIdx.x & 1023) << 8) | threadIdx.x;

  // finalize bias for this batch from the 64 partial sums (wave 0 only)
  __shared__ float s_bias;
  if (threadIdx.x < 64) {
    float s = partial[(b << 6) | threadIdx.x];
    for (int off = 32; off; off >>= 1) s += __shfl_down(s, off);
    if (threadIdx.x == 0) s_bias = fmaxf(s * (1.0f / 262144.0f), 0.0f);
  }

  const float* pb = inp + (size_t)b * 5 * HW;
  float img = pb[rem];
  float fw  = fmaxf(pb[2 * HW + rem], 0.0f);
  float fa  = fmaxf(pb[3 * HW + rem], 0.0f);
  float gw  = fmaxf(pb[4 * HW + rem], 0.0f);
  __syncthreads();
  float base = img + s_bias;

  int nf = frames[b];                               // block-uniform
  uint32_t i0 = (uint32_t)(b * 16) * (uint32_t)HW + (uint32_t)rem;

  float acc = 0.0f;
  for (int f = 0; f < nf; ++f) {
    uint32_t idx = i0 + (uint32_t)f * (uint32_t)HW; // linear idx in (8,16,512,512)
    uint32_t ub = rbits32(ku0, ku1, idx);
    uint32_t nb = rbits32(kn0, kn1, idx);

    // uniform -> t^(-fa) where t = -ln(u):
    // t^(-fa) = exp2(-fa * (log2(-log2(u)) + log2(ln2)))
    float u = unit_from_bits(ub);
    u = fminf(fmaxf(u, 1e-6f), 0.999999f);
    float l2u = LOG2F(u);                           // < 0
    float log2t = LOG2F(-l2u) - 0.52876637294f;     // + log2(ln2)
    float pw = EXP2F(-fa * log2t);

    float z = sqrt2_erfinv(fmaxf(fmaf(unit_from_bits(nb), 2.0f, -0.99999994f),
                                 -0.99999994f));
    float s = fmaf(gw, z, fmaf(fw, pw, base));
    acc += fminf(fmaxf(s, 0.0f), 1.0f);
  }
  out[(size_t)b * HW + rem] = acc * RCPF((float)nf);

  // center = clip(base + fw * (1/(fa+1))**fa, 0, 1) ; (1/(1+fa))^fa = exp2(-fa*log2(1+fa))
  float cpw = EXP2F(-fa * LOG2F(fa + 1.0f));
  float c  = fminf(fmaxf(fmaf(fw, cpw, base), 0.0f), 1.0f);
  out[ACQ_N + (size_t)b * HW + rem] = c;
}

extern "C" void kernel_launch(void* const* d_in, const int* in_sizes, int n_in,
                              void* d_out, int out_size, void* d_ws, size_t ws_size,
                              hipStream_t stream) {
  const float* inp    = (const float*)d_in[0];
  const int*   frames = (const int*)d_in[1];
  float* out = (float*)d_out;
  float* partial = (float*)d_ws;   // 512 floats

  // jax_threefry_partitionable=True (JAX >= 0.5 default):
  // split(key(42)) foldlike: ku = cipher((0,42),(0,0)), kn = cipher((0,42),(0,1))
  uint32_t ku0, ku1, kn0, kn1;
  tf2x32(0u, 42u, 0u, 0u, ku0, ku1);
  tf2x32(0u, 42u, 0u, 1u, kn0, kn1);

  bias_partial<<<dim3(512), dim3(256), 0, stream>>>(inp, partial);
  acquire_main<<<dim3(8192), dim3(256), 0, stream>>>(inp, frames, partial, out,
                                                     ku0, ku1, kn0, kn1);
}